// Round 6
// baseline (459.030 us; speedup 1.0000x reference)
//
#include <hip/hip_runtime.h>

#define NEG_SLOPE 0.2f

typedef __attribute__((ext_vector_type(8))) short bf16x8;
typedef __attribute__((ext_vector_type(4))) float f32x4;

__device__ inline unsigned short f2bf(float x) {
  unsigned int u = __float_as_uint(x);
  u += 0x7fffu + ((u >> 16) & 1u);
  return (unsigned short)(u >> 16);
}

// monotone float<->uint key for atomicMax on signed floats
__device__ inline unsigned fkey(float x) {
  unsigned u = __float_as_uint(x);
  return (u >> 31) ? ~u : (u | 0x80000000u);
}
__device__ inline float fkey_dec(unsigned k) {
  unsigned u = (k & 0x80000000u) ? (k ^ 0x80000000u) : ~k;
  return __uint_as_float(u);
}

// ---------------- CSR build ----------------

__global__ void hist_kernel(const int* __restrict__ ei, int* __restrict__ counts,
                            int E, int Etot) {
  int e = blockIdx.x * blockDim.x + threadIdx.x;
  if (e >= Etot) return;
  int d = (e < E) ? ei[E + e] : (e - E);   // self loop dst = e - E
  atomicAdd(&counts[d], 1);
}

__global__ void mean_kernel(const float* __restrict__ ea, float* __restrict__ acc, int E) {
  int i = blockIdx.x * blockDim.x + threadIdx.x;
  float s = 0.f;
  for (; i < E; i += gridDim.x * blockDim.x) s += ea[i];
#pragma unroll
  for (int off = 1; off < 64; off <<= 1) s += __shfl_xor(s, off, 64);
  if ((threadIdx.x & 63) == 0) atomicAdd(acc, s);
}

__global__ void scan_blocksum(const int* __restrict__ counts, int* __restrict__ bsum, int Nn) {
  int base = blockIdx.x * 4096 + threadIdx.x * 16;
  int s = 0;
#pragma unroll
  for (int i = 0; i < 16; i++) { int idx = base + i; if (idx < Nn) s += counts[idx]; }
#pragma unroll
  for (int off = 1; off < 64; off <<= 1) s += __shfl_xor(s, off, 64);
  __shared__ int ws_[4];
  if ((threadIdx.x & 63) == 0) ws_[threadIdx.x >> 6] = s;
  __syncthreads();
  if (threadIdx.x == 0) bsum[blockIdx.x] = ws_[0] + ws_[1] + ws_[2] + ws_[3];
}

__global__ void scan_offsets(int* bsum, int nb, int* rowptrN,
                             const float* meanacc, float* meanv, int E) {
  if (threadIdx.x == 0 && blockIdx.x == 0) {
    int acc = 0;
    for (int i = 0; i < nb; i++) { int v = bsum[i]; bsum[i] = acc; acc += v; }
    *rowptrN = acc;
    *meanv = *meanacc / (float)E;
  }
}

// writes rowptr AND cursor (saves a d2d memcpy dispatch)
__global__ void scan_final(const int* __restrict__ counts, const int* __restrict__ bsum,
                           int* __restrict__ rowptr, int* __restrict__ cursor, int Nn) {
  int base = blockIdx.x * 4096 + threadIdx.x * 16;
  int v[16]; int s = 0;
#pragma unroll
  for (int i = 0; i < 16; i++) { int idx = base + i; v[i] = (idx < Nn) ? counts[idx] : 0; s += v[i]; }
  int lane = threadIdx.x & 63, wv = threadIdx.x >> 6;
  int incl = s;
#pragma unroll
  for (int off = 1; off < 64; off <<= 1) {
    int y = __shfl_up(incl, off, 64);
    if (lane >= off) incl += y;
  }
  __shared__ int wtot[4];
  if (lane == 63) wtot[wv] = incl;
  __syncthreads();
  int run = bsum[blockIdx.x] + incl - s;
  for (int i = 0; i < wv; i++) run += wtot[i];
  for (int i = 0; i < 16; i++) {
    int idx = base + i;
    if (idx < Nn) { rowptr[idx] = run; cursor[idx] = run; }
    run += v[i];
  }
}

// scatter resolves all indirection: epack[pos] = {src, edge_attr_value}
__global__ void scatter_kernel(const int* __restrict__ ei, const float* __restrict__ eattr,
                               const float* __restrict__ meanv,
                               int* __restrict__ cursor, int2* __restrict__ epack,
                               int E, int Etot) {
  int e = blockIdx.x * blockDim.x + threadIdx.x;
  if (e >= Etot) return;
  int d, s; float ea;
  if (e < E) { d = ei[E + e]; s = ei[e]; ea = eattr[e]; }
  else       { d = e - E;     s = e - E; ea = meanv[0]; }
  int pos = atomicAdd(&cursor[d], 1);
  epack[pos] = make_int2(s, __float_as_int(ea));
}

// both layers' we_att in one launch: thread t<256 -> layer1, else layer2
__global__ void weatt_kernel(const float* __restrict__ We1, const float* __restrict__ atte1,
                             const float* __restrict__ We2, const float* __restrict__ atte2,
                             float* __restrict__ weatt1, float* __restrict__ weatt2) {
  int t = threadIdx.x;
  const float* We = (t < 256) ? We1 : We2;
  const float* at = (t < 256) ? atte1 : atte2;
  float* wo = (t < 256) ? weatt1 : weatt2;
  int i = t & 255;
  float p = We[i] * at[i];
#pragma unroll
  for (int off = 1; off < 64; off <<= 1) p += __shfl_xor(p, off, 64);
  if ((i & 63) == 0) wo[i >> 6] = p;
}

// both W transposes in one launch. blocks [0,128): W1 (K=128); [128,384): W2 (K=256)
__global__ void wtrans_kernel(const float* __restrict__ W1, unsigned short* __restrict__ Wt1,
                              const float* __restrict__ W2, unsigned short* __restrict__ Wt2) {
  int b = blockIdx.x;
  const float* W; unsigned short* Wt; int K, t;
  if (b < 128) { W = W1; Wt = Wt1; K = 128; t = b * 256 + threadIdx.x; }
  else         { W = W2; Wt = Wt2; K = 256; t = (b - 128) * 256 + threadIdx.x; }
  int n = t & 255, k = t >> 8;
  if (k >= K) return;
  Wt[(size_t)n * K + k] = f2bf(W[(size_t)k * 256 + n]);
}

// ---------------- MFMA bf16 GEMM + fused attention dots + per-head asrc max ----------------
// Y[M,256] = A[M,K] @ W[K,256].  Block: 256 thr = 4 waves, BM=32 x BN=256, BK=64.
// Wave w owns cols [w*64,w*64+64) == head w. Epilogue: Hb bf16 store, asrc/adst
// row-dots (16-lane reduce), and atomicMax of per-head asrc upper bound (fkey).

template <int AF32>
__global__ __launch_bounds__(256) void gemm_att(const void* __restrict__ Ain,
                                                const unsigned short* __restrict__ Wt,
                                                unsigned short* __restrict__ Hb,
                                                const float* __restrict__ atts,
                                                const float* __restrict__ attd,
                                                float* __restrict__ asrc,
                                                float* __restrict__ adst,
                                                unsigned* __restrict__ gmaxk,
                                                int M, int K) {
  __shared__ short As[32 * 64];    // [32][64] bf16, XOR-swizzled
  __shared__ short Bs[256 * 64];   // [256][64] bf16, XOR-swizzled
  const int tid = threadIdx.x;
  const int lane = tid & 63, wv = tid >> 6;
  const int l15 = lane & 15, l4 = lane >> 4;
  const int bm = blockIdx.x * 32;

  f32x4 acc[2][4] = {};

  for (int k0 = 0; k0 < K; k0 += 64) {
    {
      int r = tid >> 3, kc = (tid & 7) * 8;
      int gr = bm + r;
      bf16x8 v = {};
      if (gr < M) {
        if (AF32) {
          const float* src = (const float*)Ain + (size_t)gr * K + k0 + kc;
          float4 f0 = *(const float4*)src;
          float4 f1 = *(const float4*)(src + 4);
          v[0] = (short)f2bf(f0.x); v[1] = (short)f2bf(f0.y);
          v[2] = (short)f2bf(f0.z); v[3] = (short)f2bf(f0.w);
          v[4] = (short)f2bf(f1.x); v[5] = (short)f2bf(f1.y);
          v[6] = (short)f2bf(f1.z); v[7] = (short)f2bf(f1.w);
        } else {
          v = *(const bf16x8*)((const unsigned short*)Ain + (size_t)gr * K + k0 + kc);
        }
      }
      *(bf16x8*)&As[(r * 64 + kc) ^ ((r & 7) << 3)] = v;
    }
    {
      int c = tid & 7, nb = tid >> 3;
#pragma unroll
      for (int it = 0; it < 8; it++) {
        int n = nb + 32 * it;
        bf16x8 v = *(const bf16x8*)&Wt[(size_t)n * K + k0 + c * 8];
        *(bf16x8*)&Bs[(n * 64 + c * 8) ^ ((n & 7) << 3)] = v;
      }
    }
    __syncthreads();
    bf16x8 af[2][2], bfr[4][2];
#pragma unroll
    for (int rt = 0; rt < 2; rt++)
#pragma unroll
      for (int ks = 0; ks < 2; ks++) {
        int row = rt * 16 + l15;
        int kb = l4 * 8 + ks * 32;
        af[rt][ks] = *(const bf16x8*)&As[(row * 64 + kb) ^ ((row & 7) << 3)];
      }
#pragma unroll
    for (int ct = 0; ct < 4; ct++)
#pragma unroll
      for (int ks = 0; ks < 2; ks++) {
        int n = wv * 64 + ct * 16 + l15;
        int kb = l4 * 8 + ks * 32;
        bfr[ct][ks] = *(const bf16x8*)&Bs[(n * 64 + kb) ^ ((n & 7) << 3)];
      }
#pragma unroll
    for (int rt = 0; rt < 2; rt++)
#pragma unroll
      for (int ct = 0; ct < 4; ct++)
#pragma unroll
        for (int ks = 0; ks < 2; ks++)
          acc[rt][ct] = __builtin_amdgcn_mfma_f32_16x16x32_bf16(
              af[rt][ks], bfr[ct][ks], acc[rt][ct], 0, 0, 0);
    __syncthreads();
  }

  // ---- epilogue ----
  float s_att[4], d_att[4];
#pragma unroll
  for (int ct = 0; ct < 4; ct++) {
    s_att[ct] = atts[wv * 64 + ct * 16 + l15];
    d_att[ct] = attd[wv * 64 + ct * 16 + l15];
  }
  float ps[2][4] = {}, pd[2][4] = {};
#pragma unroll
  for (int rt = 0; rt < 2; rt++)
#pragma unroll
    for (int ct = 0; ct < 4; ct++)
#pragma unroll
      for (int i = 0; i < 4; i++) {
        float v = acc[rt][ct][i];
        int gr = bm + rt * 16 + l4 * 4 + i;
        if (gr < M) Hb[(size_t)gr * 256 + wv * 64 + ct * 16 + l15] = f2bf(v);
        ps[rt][i] = fmaf(v, s_att[ct], ps[rt][i]);
        pd[rt][i] = fmaf(v, d_att[ct], pd[rt][i]);
      }
#pragma unroll
  for (int rt = 0; rt < 2; rt++)
#pragma unroll
    for (int i = 0; i < 4; i++) {
#pragma unroll
      for (int off = 1; off < 16; off <<= 1) {
        ps[rt][i] += __shfl_xor(ps[rt][i], off, 64);
        pd[rt][i] += __shfl_xor(pd[rt][i], off, 64);
      }
    }
  // per-head max of asrc over this wave's 32 rows (pad rows are 0 -> only loosens bound)
  float mx = ps[0][0];
#pragma unroll
  for (int rt = 0; rt < 2; rt++)
#pragma unroll
    for (int i = 0; i < 4; i++) mx = fmaxf(mx, ps[rt][i]);
  mx = fmaxf(mx, __shfl_xor(mx, 16, 64));
  mx = fmaxf(mx, __shfl_xor(mx, 32, 64));
  if (lane == 0) atomicMax(&gmaxk[wv], fkey(mx));
  if (l15 == 0) {
#pragma unroll
    for (int rt = 0; rt < 2; rt++)
#pragma unroll
      for (int i = 0; i < 4; i++) {
        int gr = bm + rt * 16 + l4 * 4 + i;
        if (gr < M) {
          asrc[gr * 4 + wv] = ps[rt][i];
          adst[gr * 4 + wv] = pd[rt][i];
        }
      }
  }
}

// ---------------- single-pass softmax + aggregation, fixed exp-shift bound ----------------
// alpha = lrelu(asrc[s] + ad + ea*wa) <= lrelu(ad + gmax_h + max(wa,0)) = b  (monotone).
// exp(alpha - b): no online max, no rescale -> 1 exp + ~14 VALU per edge.

template <int OUTBF>
__global__ __launch_bounds__(256) void gat_agg(const unsigned short* __restrict__ Hb,
                                               const float* __restrict__ asrc,
                                               const float* __restrict__ adst,
                                               const int* __restrict__ rowptr,
                                               const int2* __restrict__ epack,
                                               const float* __restrict__ weatt,
                                               const unsigned* __restrict__ gmaxk,
                                               const float* __restrict__ bias,
                                               unsigned short* __restrict__ outb,
                                               float* __restrict__ outf, int Nn) {
  int wid = (blockIdx.x * blockDim.x + threadIdx.x) >> 6;
  int lane = threadIdx.x & 63;
  if (wid >= Nn) return;
  int beg = rowptr[wid], end = rowptr[wid + 1];
  int hh = lane >> 4;
  float wa = weatt[hh];
  float ad = adst[wid * 4 + hh];
  float braw = ad + fkey_dec(gmaxk[hh]) + fmaxf(wa, 0.f);
  float b = fmaxf(braw, NEG_SLOPE * braw);
  unsigned co = (unsigned)lane * 4u;

  float s0 = 0.f, s1 = 0.f;
  float4 a0 = {0.f, 0.f, 0.f, 0.f}, a1 = {0.f, 0.f, 0.f, 0.f};
  int p = beg;
  for (; p + 1 < end; p += 2) {
    int2 e0 = epack[p], e1 = epack[p + 1];
    float al0 = fmaf(__int_as_float(e0.y), wa, asrc[e0.x * 4 + hh] + ad);
    float al1 = fmaf(__int_as_float(e1.y), wa, asrc[e1.x * 4 + hh] + ad);
    al0 = fmaxf(al0, NEG_SLOPE * al0);
    al1 = fmaxf(al1, NEG_SLOPE * al1);
    uint2 hv0 = *(const uint2*)&Hb[(size_t)((unsigned)e0.x * 256u + co)];
    uint2 hv1 = *(const uint2*)&Hb[(size_t)((unsigned)e1.x * 256u + co)];
    float w0 = __expf(al0 - b);
    float w1 = __expf(al1 - b);
    s0 += w0;
    s1 += w1;
    a0.x = fmaf(w0, __uint_as_float(hv0.x << 16), a0.x);
    a0.y = fmaf(w0, __uint_as_float(hv0.x & 0xffff0000u), a0.y);
    a0.z = fmaf(w0, __uint_as_float(hv0.y << 16), a0.z);
    a0.w = fmaf(w0, __uint_as_float(hv0.y & 0xffff0000u), a0.w);
    a1.x = fmaf(w1, __uint_as_float(hv1.x << 16), a1.x);
    a1.y = fmaf(w1, __uint_as_float(hv1.x & 0xffff0000u), a1.y);
    a1.z = fmaf(w1, __uint_as_float(hv1.y << 16), a1.z);
    a1.w = fmaf(w1, __uint_as_float(hv1.y & 0xffff0000u), a1.w);
  }
  if (p < end) {
    int2 e0 = epack[p];
    float al0 = fmaf(__int_as_float(e0.y), wa, asrc[e0.x * 4 + hh] + ad);
    al0 = fmaxf(al0, NEG_SLOPE * al0);
    uint2 hv0 = *(const uint2*)&Hb[(size_t)((unsigned)e0.x * 256u + co)];
    float w0 = __expf(al0 - b);
    s0 += w0;
    a0.x = fmaf(w0, __uint_as_float(hv0.x << 16), a0.x);
    a0.y = fmaf(w0, __uint_as_float(hv0.x & 0xffff0000u), a0.y);
    a0.z = fmaf(w0, __uint_as_float(hv0.y << 16), a0.z);
    a0.w = fmaf(w0, __uint_as_float(hv0.y & 0xffff0000u), a0.w);
  }
  float inv = 1.f / (s0 + s1 + 1e-16f);
  float4 b4 = *(const float4*)&bias[co];
  float4 r;
  r.x = fmaf(a0.x + a1.x, inv, b4.x);
  r.y = fmaf(a0.y + a1.y, inv, b4.y);
  r.z = fmaf(a0.z + a1.z, inv, b4.z);
  r.w = fmaf(a0.w + a1.w, inv, b4.w);
  if (OUTBF) {
    unsigned lo = (unsigned)f2bf(r.x) | ((unsigned)f2bf(r.y) << 16);
    unsigned hi = (unsigned)f2bf(r.z) | ((unsigned)f2bf(r.w) << 16);
    *(uint2*)&outb[(size_t)wid * 256 + co] = make_uint2(lo, hi);
  } else {
    *(float4*)&outf[(size_t)wid * 256 + co] = r;
  }
}

// ---------------- launcher ----------------

extern "C" void kernel_launch(void* const* d_in, const int* in_sizes, int n_in,
                              void* d_out, int out_size, void* d_ws, size_t ws_size,
                              hipStream_t stream) {
  (void)n_in; (void)out_size; (void)ws_size;
  const float* x     = (const float*)d_in[0];
  const int*   ei    = (const int*)d_in[1];
  const float* eattr = (const float*)d_in[3];
  const float* W1    = (const float*)d_in[4];
  const float* We1   = (const float*)d_in[5];
  const float* atts1 = (const float*)d_in[6];
  const float* attd1 = (const float*)d_in[7];
  const float* atte1 = (const float*)d_in[8];
  const float* b1    = (const float*)d_in[9];
  const float* W2    = (const float*)d_in[10];
  const float* We2   = (const float*)d_in[11];
  const float* atts2 = (const float*)d_in[12];
  const float* attd2 = (const float*)d_in[13];
  const float* atte2 = (const float*)d_in[14];
  const float* b2    = (const float*)d_in[15];
  float* out = (float*)d_out;

  const int Nn   = in_sizes[0] / 128;   // 50000
  const int E    = in_sizes[1] / 2;     // 800000
  const int Etot = E + Nn;              // 850000

  char* p = (char*)d_ws;
  auto alloc = [&](size_t bytes) { void* r = (void*)p; p += (bytes + 255) & ~(size_t)255; return r; };
  // zero-init region (single memset): counts + meanacc + gmax keys
  int*      counts  = (int*)alloc((size_t)Nn * 4);
  float*    meanacc = (float*)alloc(4);
  unsigned* gmaxk1  = (unsigned*)alloc(16);
  unsigned* gmaxk2  = (unsigned*)alloc(16);
  char* zero_end = p;
  int*   rowptr  = (int*)alloc((size_t)(Nn + 1) * 4);
  int*   cursor  = (int*)alloc((size_t)Nn * 4);
  int2*  epack   = (int2*)alloc((size_t)Etot * 8);
  int*   bsum    = (int*)alloc(64 * 4);
  float* meanv   = (float*)alloc(4);
  float* weatt1  = (float*)alloc(16);
  float* weatt2  = (float*)alloc(16);
  float* asrc    = (float*)alloc((size_t)Nn * 4 * 4);
  float* adst    = (float*)alloc((size_t)Nn * 4 * 4);
  unsigned short* hbuf = (unsigned short*)alloc((size_t)Nn * 256 * 2);
  unsigned short* h1b  = (unsigned short*)alloc((size_t)Nn * 256 * 2);
  unsigned short* Wt1  = (unsigned short*)alloc((size_t)256 * 128 * 2);
  unsigned short* Wt2  = (unsigned short*)alloc((size_t)256 * 256 * 2);

  const int NB = (Nn + 4095) / 4096;

  hipMemsetAsync(counts, 0, (size_t)(zero_end - (char*)counts), stream);

  hist_kernel<<<(Etot + 255) / 256, 256, 0, stream>>>(ei, counts, E, Etot);
  mean_kernel<<<512, 256, 0, stream>>>(eattr, meanacc, E);
  scan_blocksum<<<NB, 256, 0, stream>>>(counts, bsum, Nn);
  scan_offsets<<<1, 64, 0, stream>>>(bsum, NB, rowptr + Nn, meanacc, meanv, E);
  scan_final<<<NB, 256, 0, stream>>>(counts, bsum, rowptr, cursor, Nn);
  scatter_kernel<<<(Etot + 255) / 256, 256, 0, stream>>>(ei, eattr, meanv, cursor, epack, E, Etot);
  weatt_kernel<<<1, 512, 0, stream>>>(We1, atte1, We2, atte2, weatt1, weatt2);
  wtrans_kernel<<<384, 256, 0, stream>>>(W1, Wt1, W2, Wt2);

  const int gemmBlocks = (Nn + 31) / 32;
  const int nodeBlocks = (Nn + 3) / 4;

  // ---- layer 1 ----
  gemm_att<1><<<gemmBlocks, 256, 0, stream>>>(x, Wt1, hbuf, atts1, attd1,
                                              asrc, adst, gmaxk1, Nn, 128);
  gat_agg<1><<<nodeBlocks, 256, 0, stream>>>(hbuf, asrc, adst, rowptr, epack,
                                             weatt1, gmaxk1, b1, h1b, nullptr, Nn);
  // ---- layer 2 ----
  gemm_att<0><<<gemmBlocks, 256, 0, stream>>>(h1b, Wt2, hbuf, atts2, attd2,
                                              asrc, adst, gmaxk2, Nn, 256);
  gat_agg<0><<<nodeBlocks, 256, 0, stream>>>(hbuf, asrc, adst, rowptr, epack,
                                             weatt2, gmaxk2, b2, nullptr, out, Nn);
}

// Round 7
// 350.192 us; speedup vs baseline: 1.3108x; 1.3108x over previous
//
#include <hip/hip_runtime.h>

#define NEG_SLOPE 0.2f

typedef __attribute__((ext_vector_type(8))) short bf16x8;
typedef __attribute__((ext_vector_type(4))) float f32x4;

__device__ inline unsigned short f2bf(float x) {
  unsigned int u = __float_as_uint(x);
  u += 0x7fffu + ((u >> 16) & 1u);
  return (unsigned short)(u >> 16);
}

// monotone float<->uint key for atomicMax on signed floats
__device__ inline unsigned fkey(float x) {
  unsigned u = __float_as_uint(x);
  return (u >> 31) ? ~u : (u | 0x80000000u);
}
__device__ inline float fkey_dec(unsigned k) {
  unsigned u = (k & 0x80000000u) ? (k ^ 0x80000000u) : ~k;
  return __uint_as_float(u);
}

// ---------------- CSR build ----------------

__global__ void hist_kernel(const int* __restrict__ ei, int* __restrict__ counts,
                            int E, int Etot) {
  int e = blockIdx.x * blockDim.x + threadIdx.x;
  if (e >= Etot) return;
  int d = (e < E) ? ei[E + e] : (e - E);   // self loop dst = e - E
  atomicAdd(&counts[d], 1);
}

__global__ void mean_kernel(const float* __restrict__ ea, float* __restrict__ acc, int E) {
  int i = blockIdx.x * blockDim.x + threadIdx.x;
  float s = 0.f;
  for (; i < E; i += gridDim.x * blockDim.x) s += ea[i];
#pragma unroll
  for (int off = 1; off < 64; off <<= 1) s += __shfl_xor(s, off, 64);
  if ((threadIdx.x & 63) == 0) atomicAdd(acc, s);
}

__global__ void scan_blocksum(const int* __restrict__ counts, int* __restrict__ bsum, int Nn) {
  int base = blockIdx.x * 4096 + threadIdx.x * 16;
  int s = 0;
#pragma unroll
  for (int i = 0; i < 16; i++) { int idx = base + i; if (idx < Nn) s += counts[idx]; }
#pragma unroll
  for (int off = 1; off < 64; off <<= 1) s += __shfl_xor(s, off, 64);
  __shared__ int ws_[4];
  if ((threadIdx.x & 63) == 0) ws_[threadIdx.x >> 6] = s;
  __syncthreads();
  if (threadIdx.x == 0) bsum[blockIdx.x] = ws_[0] + ws_[1] + ws_[2] + ws_[3];
}

__global__ void scan_offsets(int* bsum, int nb, int* rowptrN,
                             const float* meanacc, float* meanv, int E) {
  if (threadIdx.x == 0 && blockIdx.x == 0) {
    int acc = 0;
    for (int i = 0; i < nb; i++) { int v = bsum[i]; bsum[i] = acc; acc += v; }
    *rowptrN = acc;
    *meanv = *meanacc / (float)E;
  }
}

// writes rowptr AND cursor (saves a d2d memcpy dispatch)
__global__ void scan_final(const int* __restrict__ counts, const int* __restrict__ bsum,
                           int* __restrict__ rowptr, int* __restrict__ cursor, int Nn) {
  int base = blockIdx.x * 4096 + threadIdx.x * 16;
  int v[16]; int s = 0;
#pragma unroll
  for (int i = 0; i < 16; i++) { int idx = base + i; v[i] = (idx < Nn) ? counts[idx] : 0; s += v[i]; }
  int lane = threadIdx.x & 63, wv = threadIdx.x >> 6;
  int incl = s;
#pragma unroll
  for (int off = 1; off < 64; off <<= 1) {
    int y = __shfl_up(incl, off, 64);
    if (lane >= off) incl += y;
  }
  __shared__ int wtot[4];
  if (lane == 63) wtot[wv] = incl;
  __syncthreads();
  int run = bsum[blockIdx.x] + incl - s;
  for (int i = 0; i < wv; i++) run += wtot[i];
  for (int i = 0; i < 16; i++) {
    int idx = base + i;
    if (idx < Nn) { rowptr[idx] = run; cursor[idx] = run; }
    run += v[i];
  }
}

// scatter resolves all indirection: epack[pos] = {src, edge_attr_value}
__global__ void scatter_kernel(const int* __restrict__ ei, const float* __restrict__ eattr,
                               const float* __restrict__ meanv,
                               int* __restrict__ cursor, int2* __restrict__ epack,
                               int E, int Etot) {
  int e = blockIdx.x * blockDim.x + threadIdx.x;
  if (e >= Etot) return;
  int d, s; float ea;
  if (e < E) { d = ei[E + e]; s = ei[e]; ea = eattr[e]; }
  else       { d = e - E;     s = e - E; ea = meanv[0]; }
  int pos = atomicAdd(&cursor[d], 1);
  epack[pos] = make_int2(s, __float_as_int(ea));
}

// both layers' we_att in one launch: thread t<256 -> layer1, else layer2
__global__ void weatt_kernel(const float* __restrict__ We1, const float* __restrict__ atte1,
                             const float* __restrict__ We2, const float* __restrict__ atte2,
                             float* __restrict__ weatt1, float* __restrict__ weatt2) {
  int t = threadIdx.x;
  const float* We = (t < 256) ? We1 : We2;
  const float* at = (t < 256) ? atte1 : atte2;
  float* wo = (t < 256) ? weatt1 : weatt2;
  int i = t & 255;
  float p = We[i] * at[i];
#pragma unroll
  for (int off = 1; off < 64; off <<= 1) p += __shfl_xor(p, off, 64);
  if ((i & 63) == 0) wo[i >> 6] = p;
}

// both W transposes in one launch. blocks [0,128): W1 (K=128); [128,384): W2 (K=256)
__global__ void wtrans_kernel(const float* __restrict__ W1, unsigned short* __restrict__ Wt1,
                              const float* __restrict__ W2, unsigned short* __restrict__ Wt2) {
  int b = blockIdx.x;
  const float* W; unsigned short* Wt; int K, t;
  if (b < 128) { W = W1; Wt = Wt1; K = 128; t = b * 256 + threadIdx.x; }
  else         { W = W2; Wt = Wt2; K = 256; t = (b - 128) * 256 + threadIdx.x; }
  int n = t & 255, k = t >> 8;
  if (k >= K) return;
  Wt[(size_t)n * K + k] = f2bf(W[(size_t)k * 256 + n]);
}

// ---------------- MFMA bf16 GEMM + fused attention dots + per-head asrc max ----------------
// Y[M,256] = A[M,K] @ W[K,256].  Block: 512 thr = 8 waves (2M x 4N), BM=128 x
// BN=256, BK=64.  Wave wv: rows [wm*64, +64), cols [wn*64, +64) == head wn.
// 32 MFMAs per wave per K-step between barriers (vs 16 in round 6's BM=32).
// Epilogue: Hb bf16 store, asrc/adst row-dots (16-lane reduce), atomicMax of
// per-head asrc upper bound into padded (128B-strided) slots.

template <int AF32>
__global__ __launch_bounds__(512) void gemm_att(const void* __restrict__ Ain,
                                                const unsigned short* __restrict__ Wt,
                                                unsigned short* __restrict__ Hb,
                                                const float* __restrict__ atts,
                                                const float* __restrict__ attd,
                                                float* __restrict__ asrc,
                                                float* __restrict__ adst,
                                                unsigned* __restrict__ gmaxk,
                                                int M, int K) {
  __shared__ short As[128 * 64];   // [128][64] bf16, XOR-swizzled
  __shared__ short Bs[256 * 64];   // [256][64] bf16, XOR-swizzled
  const int tid = threadIdx.x;
  const int lane = tid & 63, wv = tid >> 6;
  const int wm = wv >> 2, wn = wv & 3;        // wave row-half, head
  const int l15 = lane & 15, l4 = lane >> 4;
  const int bm = blockIdx.x * 128;

  f32x4 acc[4][4] = {};

  for (int k0 = 0; k0 < K; k0 += 64) {
    // ---- stage A tile [128 rows][64 k]: thread covers rows r0, r0+64 ----
    {
      int r0 = tid >> 3, kc = (tid & 7) * 8;
#pragma unroll
      for (int rr = 0; rr < 2; rr++) {
        int r = r0 + rr * 64;
        int gr = bm + r;
        bf16x8 v = {};
        if (gr < M) {
          if (AF32) {
            const float* src = (const float*)Ain + (size_t)gr * K + k0 + kc;
            float4 f0 = *(const float4*)src;
            float4 f1 = *(const float4*)(src + 4);
            v[0] = (short)f2bf(f0.x); v[1] = (short)f2bf(f0.y);
            v[2] = (short)f2bf(f0.z); v[3] = (short)f2bf(f0.w);
            v[4] = (short)f2bf(f1.x); v[5] = (short)f2bf(f1.y);
            v[6] = (short)f2bf(f1.z); v[7] = (short)f2bf(f1.w);
          } else {
            v = *(const bf16x8*)((const unsigned short*)Ain + (size_t)gr * K + k0 + kc);
          }
        }
        *(bf16x8*)&As[(r * 64 + kc) ^ ((r & 7) << 3)] = v;
      }
    }
    // ---- stage B tile [256 n][64 k] from Wt[n][K] ----
    {
      int c = tid & 7, nb = tid >> 3;
#pragma unroll
      for (int it = 0; it < 4; it++) {
        int n = nb + 64 * it;
        bf16x8 v = *(const bf16x8*)&Wt[(size_t)n * K + k0 + c * 8];
        *(bf16x8*)&Bs[(n * 64 + c * 8) ^ ((n & 7) << 3)] = v;
      }
    }
    __syncthreads();
    bf16x8 af[4][2], bfr[4][2];
#pragma unroll
    for (int rt = 0; rt < 4; rt++)
#pragma unroll
      for (int ks = 0; ks < 2; ks++) {
        int row = wm * 64 + rt * 16 + l15;
        int kb = l4 * 8 + ks * 32;
        af[rt][ks] = *(const bf16x8*)&As[(row * 64 + kb) ^ ((row & 7) << 3)];
      }
#pragma unroll
    for (int ct = 0; ct < 4; ct++)
#pragma unroll
      for (int ks = 0; ks < 2; ks++) {
        int n = wn * 64 + ct * 16 + l15;
        int kb = l4 * 8 + ks * 32;
        bfr[ct][ks] = *(const bf16x8*)&Bs[(n * 64 + kb) ^ ((n & 7) << 3)];
      }
#pragma unroll
    for (int rt = 0; rt < 4; rt++)
#pragma unroll
      for (int ct = 0; ct < 4; ct++)
#pragma unroll
        for (int ks = 0; ks < 2; ks++)
          acc[rt][ct] = __builtin_amdgcn_mfma_f32_16x16x32_bf16(
              af[rt][ks], bfr[ct][ks], acc[rt][ct], 0, 0, 0);
    __syncthreads();
  }

  // ---- epilogue: Hb bf16 store + fused a_src/a_dst + per-head max ----
  float s_att[4], d_att[4];
#pragma unroll
  for (int ct = 0; ct < 4; ct++) {
    s_att[ct] = atts[wn * 64 + ct * 16 + l15];
    d_att[ct] = attd[wn * 64 + ct * 16 + l15];
  }
  float ps[4][4] = {}, pd[4][4] = {};
#pragma unroll
  for (int rt = 0; rt < 4; rt++)
#pragma unroll
    for (int ct = 0; ct < 4; ct++)
#pragma unroll
      for (int i = 0; i < 4; i++) {
        float v = acc[rt][ct][i];
        int gr = bm + wm * 64 + rt * 16 + l4 * 4 + i;
        if (gr < M) Hb[(size_t)gr * 256 + wn * 64 + ct * 16 + l15] = f2bf(v);
        ps[rt][i] = fmaf(v, s_att[ct], ps[rt][i]);
        pd[rt][i] = fmaf(v, d_att[ct], pd[rt][i]);
      }
#pragma unroll
  for (int rt = 0; rt < 4; rt++)
#pragma unroll
    for (int i = 0; i < 4; i++) {
#pragma unroll
      for (int off = 1; off < 16; off <<= 1) {
        ps[rt][i] += __shfl_xor(ps[rt][i], off, 64);
        pd[rt][i] += __shfl_xor(pd[rt][i], off, 64);
      }
    }
  // per-head max of asrc over this wave's 64 rows (pad rows contribute 0 -> bound loosens only)
  float mx = ps[0][0];
#pragma unroll
  for (int rt = 0; rt < 4; rt++)
#pragma unroll
    for (int i = 0; i < 4; i++) mx = fmaxf(mx, ps[rt][i]);
  mx = fmaxf(mx, __shfl_xor(mx, 16, 64));
  mx = fmaxf(mx, __shfl_xor(mx, 32, 64));
  if (lane == 0) atomicMax(&gmaxk[wn * 32], fkey(mx));   // 128B-strided slots
  if (l15 == 0) {
#pragma unroll
    for (int rt = 0; rt < 4; rt++)
#pragma unroll
      for (int i = 0; i < 4; i++) {
        int gr = bm + wm * 64 + rt * 16 + l4 * 4 + i;
        if (gr < M) {
          asrc[gr * 4 + wn] = ps[rt][i];
          adst[gr * 4 + wn] = pd[rt][i];
        }
      }
  }
}

// ---------------- single-pass softmax + aggregation, fixed exp-shift bound ----------------
// alpha = lrelu(asrc[s] + ad + ea*wa) <= lrelu(ad + gmax_h + max(wa,0)) = b  (monotone).
// exp(alpha - b): no online max, no rescale -> 1 exp + ~14 VALU per edge.

template <int OUTBF>
__global__ __launch_bounds__(256) void gat_agg(const unsigned short* __restrict__ Hb,
                                               const float* __restrict__ asrc,
                                               const float* __restrict__ adst,
                                               const int* __restrict__ rowptr,
                                               const int2* __restrict__ epack,
                                               const float* __restrict__ weatt,
                                               const unsigned* __restrict__ gmaxk,
                                               const float* __restrict__ bias,
                                               unsigned short* __restrict__ outb,
                                               float* __restrict__ outf, int Nn) {
  int wid = (blockIdx.x * blockDim.x + threadIdx.x) >> 6;
  int lane = threadIdx.x & 63;
  if (wid >= Nn) return;
  int beg = rowptr[wid], end = rowptr[wid + 1];
  int hh = lane >> 4;
  float wa = weatt[hh];
  float ad = adst[wid * 4 + hh];
  float braw = ad + fkey_dec(gmaxk[hh * 32]) + fmaxf(wa, 0.f);
  float b = fmaxf(braw, NEG_SLOPE * braw);
  unsigned co = (unsigned)lane * 4u;

  float s0 = 0.f, s1 = 0.f;
  float4 a0 = {0.f, 0.f, 0.f, 0.f}, a1 = {0.f, 0.f, 0.f, 0.f};
  int p = beg;
  for (; p + 1 < end; p += 2) {
    int2 e0 = epack[p], e1 = epack[p + 1];
    float al0 = fmaf(__int_as_float(e0.y), wa, asrc[e0.x * 4 + hh] + ad);
    float al1 = fmaf(__int_as_float(e1.y), wa, asrc[e1.x * 4 + hh] + ad);
    al0 = fmaxf(al0, NEG_SLOPE * al0);
    al1 = fmaxf(al1, NEG_SLOPE * al1);
    uint2 hv0 = *(const uint2*)&Hb[(size_t)((unsigned)e0.x * 256u + co)];
    uint2 hv1 = *(const uint2*)&Hb[(size_t)((unsigned)e1.x * 256u + co)];
    float w0 = __expf(al0 - b);
    float w1 = __expf(al1 - b);
    s0 += w0;
    s1 += w1;
    a0.x = fmaf(w0, __uint_as_float(hv0.x << 16), a0.x);
    a0.y = fmaf(w0, __uint_as_float(hv0.x & 0xffff0000u), a0.y);
    a0.z = fmaf(w0, __uint_as_float(hv0.y << 16), a0.z);
    a0.w = fmaf(w0, __uint_as_float(hv0.y & 0xffff0000u), a0.w);
    a1.x = fmaf(w1, __uint_as_float(hv1.x << 16), a1.x);
    a1.y = fmaf(w1, __uint_as_float(hv1.x & 0xffff0000u), a1.y);
    a1.z = fmaf(w1, __uint_as_float(hv1.y << 16), a1.z);
    a1.w = fmaf(w1, __uint_as_float(hv1.y & 0xffff0000u), a1.w);
  }
  if (p < end) {
    int2 e0 = epack[p];
    float al0 = fmaf(__int_as_float(e0.y), wa, asrc[e0.x * 4 + hh] + ad);
    al0 = fmaxf(al0, NEG_SLOPE * al0);
    uint2 hv0 = *(const uint2*)&Hb[(size_t)((unsigned)e0.x * 256u + co)];
    float w0 = __expf(al0 - b);
    s0 += w0;
    a0.x = fmaf(w0, __uint_as_float(hv0.x << 16), a0.x);
    a0.y = fmaf(w0, __uint_as_float(hv0.x & 0xffff0000u), a0.y);
    a0.z = fmaf(w0, __uint_as_float(hv0.y << 16), a0.z);
    a0.w = fmaf(w0, __uint_as_float(hv0.y & 0xffff0000u), a0.w);
  }
  float inv = 1.f / (s0 + s1 + 1e-16f);
  float4 b4 = *(const float4*)&bias[co];
  float4 r;
  r.x = fmaf(a0.x + a1.x, inv, b4.x);
  r.y = fmaf(a0.y + a1.y, inv, b4.y);
  r.z = fmaf(a0.z + a1.z, inv, b4.z);
  r.w = fmaf(a0.w + a1.w, inv, b4.w);
  if (OUTBF) {
    unsigned lo = (unsigned)f2bf(r.x) | ((unsigned)f2bf(r.y) << 16);
    unsigned hi = (unsigned)f2bf(r.z) | ((unsigned)f2bf(r.w) << 16);
    *(uint2*)&outb[(size_t)wid * 256 + co] = make_uint2(lo, hi);
  } else {
    *(float4*)&outf[(size_t)wid * 256 + co] = r;
  }
}

// ---------------- launcher ----------------

extern "C" void kernel_launch(void* const* d_in, const int* in_sizes, int n_in,
                              void* d_out, int out_size, void* d_ws, size_t ws_size,
                              hipStream_t stream) {
  (void)n_in; (void)out_size; (void)ws_size;
  const float* x     = (const float*)d_in[0];
  const int*   ei    = (const int*)d_in[1];
  const float* eattr = (const float*)d_in[3];
  const float* W1    = (const float*)d_in[4];
  const float* We1   = (const float*)d_in[5];
  const float* atts1 = (const float*)d_in[6];
  const float* attd1 = (const float*)d_in[7];
  const float* atte1 = (const float*)d_in[8];
  const float* b1    = (const float*)d_in[9];
  const float* W2    = (const float*)d_in[10];
  const float* We2   = (const float*)d_in[11];
  const float* atts2 = (const float*)d_in[12];
  const float* attd2 = (const float*)d_in[13];
  const float* atte2 = (const float*)d_in[14];
  const float* b2    = (const float*)d_in[15];
  float* out = (float*)d_out;

  const int Nn   = in_sizes[0] / 128;   // 50000
  const int E    = in_sizes[1] / 2;     // 800000
  const int Etot = E + Nn;              // 850000

  char* p = (char*)d_ws;
  auto alloc = [&](size_t bytes) { void* r = (void*)p; p += (bytes + 255) & ~(size_t)255; return r; };
  // zero-init region (single memset): counts + meanacc + gmax keys (padded)
  int*      counts  = (int*)alloc((size_t)Nn * 4);
  float*    meanacc = (float*)alloc(4);
  unsigned* gmaxk1  = (unsigned*)alloc(512);   // 4 heads x 128B stride
  unsigned* gmaxk2  = (unsigned*)alloc(512);
  char* zero_end = p;
  int*   rowptr  = (int*)alloc((size_t)(Nn + 1) * 4);
  int*   cursor  = (int*)alloc((size_t)Nn * 4);
  int2*  epack   = (int2*)alloc((size_t)Etot * 8);
  int*   bsum    = (int*)alloc(64 * 4);
  float* meanv   = (float*)alloc(4);
  float* weatt1  = (float*)alloc(16);
  float* weatt2  = (float*)alloc(16);
  float* asrc    = (float*)alloc((size_t)Nn * 4 * 4);
  float* adst    = (float*)alloc((size_t)Nn * 4 * 4);
  unsigned short* hbuf = (unsigned short*)alloc((size_t)Nn * 256 * 2);
  unsigned short* h1b  = (unsigned short*)alloc((size_t)Nn * 256 * 2);
  unsigned short* Wt1  = (unsigned short*)alloc((size_t)256 * 128 * 2);
  unsigned short* Wt2  = (unsigned short*)alloc((size_t)256 * 256 * 2);

  const int NB = (Nn + 4095) / 4096;

  hipMemsetAsync(counts, 0, (size_t)(zero_end - (char*)counts), stream);

  hist_kernel<<<(Etot + 255) / 256, 256, 0, stream>>>(ei, counts, E, Etot);
  mean_kernel<<<512, 256, 0, stream>>>(eattr, meanacc, E);
  scan_blocksum<<<NB, 256, 0, stream>>>(counts, bsum, Nn);
  scan_offsets<<<1, 64, 0, stream>>>(bsum, NB, rowptr + Nn, meanacc, meanv, E);
  scan_final<<<NB, 256, 0, stream>>>(counts, bsum, rowptr, cursor, Nn);
  scatter_kernel<<<(Etot + 255) / 256, 256, 0, stream>>>(ei, eattr, meanv, cursor, epack, E, Etot);
  weatt_kernel<<<1, 512, 0, stream>>>(We1, atte1, We2, atte2, weatt1, weatt2);
  wtrans_kernel<<<384, 256, 0, stream>>>(W1, Wt1, W2, Wt2);

  const int gemmBlocks = (Nn + 127) / 128;   // 391
  const int nodeBlocks = (Nn + 3) / 4;

  // ---- layer 1 ----
  gemm_att<1><<<gemmBlocks, 512, 0, stream>>>(x, Wt1, hbuf, atts1, attd1,
                                              asrc, adst, gmaxk1, Nn, 128);
  gat_agg<1><<<nodeBlocks, 256, 0, stream>>>(hbuf, asrc, adst, rowptr, epack,
                                             weatt1, gmaxk1, b1, h1b, nullptr, Nn);
  // ---- layer 2 ----
  gemm_att<0><<<gemmBlocks, 512, 0, stream>>>(h1b, Wt2, hbuf, atts2, attd2,
                                              asrc, adst, gmaxk2, Nn, 256);
  gat_agg<0><<<nodeBlocks, 256, 0, stream>>>(hbuf, asrc, adst, rowptr, epack,
                                             weatt2, gmaxk2, b2, nullptr, out, Nn);
}